// Round 14
// baseline (1034.451 us; speedup 1.0000x reference)
//
#include <hip/hip_runtime.h>
#include <hip/hip_bf16.h>

// GINE 3-conv GNN. Coarse-bucket counting sort (NO full dst-sort, kbucket
// deleted) + fused conv kernels with LDS-atomic per-bucket aggregation:
//   build: khist1/kscan_a/kscan_b/kscatter1 (2048 blocks, LDS cursors, zero
//     global atomics). Edges land grouped by bucket (dst>>7), RANDOM dst order
//     within bucket -> LDS atomicAdd aggregation is nearly conflict-free
//     (round-11's serializer was the sorted order, not the atomics).
//   convE: one block per 128-node bucket (512 thr). Thread-per-slot edge MLP
//     in registers (round-12 verbatim math); nrec 64B line gives Pa+X in one
//     gather; Pc gathers hit a 4KB L1-resident window; msg -> aggT[128][17]
//     LDS atomics; coalesced plain-store writeback (no kzero, no global
//     atomics, no segment scan).
// N=100000, E=3200000, H=16. fp32 in/out; edge_index int32 rows [src | dst].
//
// ws (137.6 MB): ebuf[E][16]bf16; srec[E]u64 {src:17,dst:17,eid:22};
//   nrec[N][32]bf16 {Pa|X} + Pc[N][16]bf16 (hist[782][2048] 6.4MB aliased
//   under nrec/Pc, dead before prep1 which runs after the build); binsum/binbase.
// d_out out_e region: ea_s[E]8B (dead after conv1E) + agg[N][16]f32 (dead
//   before khead writes out_e; consumed by node kernels first).

#define NN 100000
#define NE 3200000
#define NBKT 782          // ceil(NN/128)
#define BSHIFT 7
#define LMASK 127
#define NBLK1 2048        // pass-1 blocks

__device__ __forceinline__ float bf2f(unsigned int h) {
    unsigned int u = h << 16;
    float f; __builtin_memcpy(&f, &u, 4); return f;
}
__device__ __forceinline__ unsigned short f2bf(float f) {
    unsigned int u; __builtin_memcpy(&u, &f, 4);
    u += 0x7fffu + ((u >> 16) & 1u);          // RNE
    return (unsigned short)(u >> 16);
}
__device__ __forceinline__ void unpk4(uint2 w, float* r) {
    r[0] = bf2f(w.x & 0xffffu); r[1] = bf2f(w.x >> 16);
    r[2] = bf2f(w.y & 0xffffu); r[3] = bf2f(w.y >> 16);
}
__device__ __forceinline__ void ldbf16x16(const unsigned short* p, float* r) {
    const uint4* q = reinterpret_cast<const uint4*>(p);
    uint4 a = q[0], b = q[1];
    unsigned int w[8] = {a.x, a.y, a.z, a.w, b.x, b.y, b.z, b.w};
    #pragma unroll
    for (int k = 0; k < 8; ++k) {
        r[2*k]   = bf2f(w[k] & 0xffffu);
        r[2*k+1] = bf2f(w[k] >> 16);
    }
}
__device__ __forceinline__ void stbf16x16(unsigned short* p, const float* r) {
    unsigned int w[8];
    #pragma unroll
    for (int k = 0; k < 8; ++k)
        w[k] = (unsigned int)f2bf(r[2*k]) | ((unsigned int)f2bf(r[2*k+1]) << 16);
    uint4* q = reinterpret_cast<uint4*>(p);
    q[0] = make_uint4(w[0], w[1], w[2], w[3]);
    q[1] = make_uint4(w[4], w[5], w[6], w[7]);
}
// nrec row: group g (dims 4g..4g+3): [g*8 .. g*8+3]=Pa, [g*8+4 .. g*8+7]=X
__device__ __forceinline__ void st_nrec16(unsigned short* p, const float* pa, const float* xv) {
    #pragma unroll
    for (int g = 0; g < 4; ++g) {
        uint4 w;
        w.x = (unsigned)f2bf(pa[4*g])   | ((unsigned)f2bf(pa[4*g+1]) << 16);
        w.y = (unsigned)f2bf(pa[4*g+2]) | ((unsigned)f2bf(pa[4*g+3]) << 16);
        w.z = (unsigned)f2bf(xv[4*g])   | ((unsigned)f2bf(xv[4*g+1]) << 16);
        w.w = (unsigned)f2bf(xv[4*g+2]) | ((unsigned)f2bf(xv[4*g+3]) << 16);
        *reinterpret_cast<uint4*>(p + g*8) = w;
    }
}
__device__ __forceinline__ void ld_nrec16(const unsigned short* p, float* pa, float* xv) {
    #pragma unroll
    for (int g = 0; g < 4; ++g) {
        uint4 w = *reinterpret_cast<const uint4*>(p + g*8);
        unpk4(make_uint2(w.x, w.y), pa + 4*g);
        unpk4(make_uint2(w.z, w.w), xv + 4*g);
    }
}
__device__ __forceinline__ void ld_X16(const unsigned short* p, float* xv) {
    #pragma unroll
    for (int g = 0; g < 4; ++g) {
        uint2 w = *reinterpret_cast<const uint2*>(p + g*8 + 4);
        unpk4(w, xv + 4*g);
    }
}

// ---------------- build: coarse counting sort (no global atomics) ----------------

__global__ void khist1(const int* __restrict__ ei, int* __restrict__ hist) {
    __shared__ int h[NBKT];
    int blk = blockIdx.x, tid = threadIdx.x;
    for (int b = tid; b < NBKT; b += 256) h[b] = 0;
    __syncthreads();
    int e0 = (int)((long long)blk * NE / NBLK1);
    int e1 = (int)((long long)(blk + 1) * NE / NBLK1);
    for (int e = e0 + tid; e < e1; e += 256)
        atomicAdd(&h[ei[NE + e] >> BSHIFT], 1);     // LDS atomic
    __syncthreads();
    for (int b = tid; b < NBKT; b += 256) hist[b * NBLK1 + blk] = h[b];
}

// per-bin exclusive scan over 2048 blocks; 1024 threads, two halves (proven r13).
__global__ void kscan_a(int* __restrict__ hist, int* __restrict__ binsum) {
    __shared__ int s[1024];
    int b = blockIdx.x, t = threadIdx.x;
    int base = b * NBLK1;
    int v0 = hist[base + t];
    s[t] = v0; __syncthreads();
    for (int off = 1; off < 1024; off <<= 1) {
        int u = (t >= off) ? s[t - off] : 0;
        __syncthreads();
        s[t] += u;
        __syncthreads();
    }
    int excl0 = s[t] - v0;
    int tot0 = s[1023];
    __syncthreads();
    int v1 = hist[base + 1024 + t];
    s[t] = v1; __syncthreads();
    for (int off = 1; off < 1024; off <<= 1) {
        int u = (t >= off) ? s[t - off] : 0;
        __syncthreads();
        s[t] += u;
        __syncthreads();
    }
    int excl1 = s[t] - v1 + tot0;
    hist[base + t] = excl0;
    hist[base + 1024 + t] = excl1;
    if (t == 1023) binsum[b] = s[1023] + tot0;
}

__global__ void kscan_b(const int* __restrict__ binsum, int* __restrict__ binbase) {
    __shared__ int s[1024];
    int t = threadIdx.x;
    int v = (t < NBKT) ? binsum[t] : 0;
    s[t] = v; __syncthreads();
    for (int off = 1; off < 1024; off <<= 1) {
        int u = (t >= off) ? s[t - off] : 0;
        __syncthreads();
        s[t] += u;
        __syncthreads();
    }
    if (t < NBKT) binbase[t] = s[t] - v;
    if (t == NBKT - 1) binbase[NBKT] = s[t];        // == NE
}

// scatter into coarse buckets: srec (ws) + ea_s (out_e region), 8B each.
__global__ void kscatter1(const int* __restrict__ ei, const float* __restrict__ ea,
                          const int* __restrict__ hist, const int* __restrict__ binbase,
                          unsigned long long* __restrict__ srec,
                          unsigned long long* __restrict__ ea_s) {
    __shared__ int cur[NBKT];
    int blk = blockIdx.x, tid = threadIdx.x;
    for (int b = tid; b < NBKT; b += 256)
        cur[b] = binbase[b] + hist[b * NBLK1 + blk];
    __syncthreads();
    int e0 = (int)((long long)blk * NE / NBLK1);
    int e1 = (int)((long long)(blk + 1) * NE / NBLK1);
    for (int e = e0 + tid; e < e1; e += 256) {
        int s = ei[e], d = ei[NE + e];
        float f0 = ea[(size_t)3*e], f1 = ea[(size_t)3*e+1], f2 = ea[(size_t)3*e+2];
        int pos = atomicAdd(&cur[d >> BSHIFT], 1);  // LDS atomic
        srec[pos] = (unsigned long long)(unsigned int)s
                  | ((unsigned long long)(unsigned int)d << 17)
                  | ((unsigned long long)(unsigned int)e << 34);
        ea_s[pos] = (unsigned long long)((unsigned int)f2bf(f0) | ((unsigned int)f2bf(f1) << 16))
                  | ((unsigned long long)(unsigned int)f2bf(f2) << 32);
    }
}

// ---------------- node-side kernels (verified, verbatim) ----------------

__global__ void prep1(const float* __restrict__ x, const float* __restrict__ ew1,
                      unsigned short* __restrict__ nrec, unsigned short* __restrict__ Pc) {
    int n = blockIdx.x * blockDim.x + threadIdx.x;
    if (n >= NN) return;
    float x0 = x[3*n], x1 = x[3*n+1], x2 = x[3*n+2];
    float pa[16], pc[16], xv[16];
    #pragma unroll
    for (int j = 0; j < 16; ++j) {
        pa[j] = x0*ew1[0*16+j] + x1*ew1[1*16+j] + x2*ew1[2*16+j];
        pc[j] = x0*ew1[6*16+j] + x1*ew1[7*16+j] + x2*ew1[8*16+j];
        xv[j] = 0.f;
    }
    xv[0] = x0; xv[1] = x1; xv[2] = x2;
    st_nrec16(nrec + (size_t)n*32, pa, xv);
    stbf16x16(Pc + (size_t)n*16, pc);
}

__global__ void conv1_node(const float* __restrict__ agg, const float* __restrict__ x,
                           const float* __restrict__ nw1, const float* __restrict__ nb1,
                           const float* __restrict__ nw2, const float* __restrict__ nb2,
                           const float* __restrict__ next_ew1,
                           unsigned short* __restrict__ nrec, unsigned short* __restrict__ Pc) {
    int n = blockIdx.x * blockDim.x + threadIdx.x;
    if (n >= NN) return;
    float o0 = agg[(size_t)n*16+0] + x[3*n];
    float o1 = agg[(size_t)n*16+1] + x[3*n+1];
    float o2 = agg[(size_t)n*16+2] + x[3*n+2];
    float h[16];
    #pragma unroll
    for (int j = 0; j < 16; ++j)
        h[j] = fmaxf(nb1[j] + o0*nw1[0*16+j] + o1*nw1[1*16+j] + o2*nw1[2*16+j], 0.f);
    float xn[16];
    #pragma unroll
    for (int j = 0; j < 16; ++j) {
        float a = nb2[j];
        #pragma unroll
        for (int i = 0; i < 16; ++i) a = fmaf(h[i], nw2[i*16+j], a);
        xn[j] = fmaxf(a, 0.f);
    }
    float pa[16], pc[16];
    #pragma unroll
    for (int j = 0; j < 16; ++j) {
        float sa = 0.f, sc = 0.f;
        #pragma unroll
        for (int i = 0; i < 16; ++i) {
            sa = fmaf(xn[i], next_ew1[i*16+j], sa);
            sc = fmaf(xn[i], next_ew1[(32+i)*16+j], sc);
        }
        pa[j] = sa; pc[j] = sc;
    }
    st_nrec16(nrec + (size_t)n*32, pa, xn);
    stbf16x16(Pc + (size_t)n*16, pc);
}

__global__ void node_mid(const float* __restrict__ agg,
                         const float* __restrict__ nw1, const float* __restrict__ nb1,
                         const float* __restrict__ nw2, const float* __restrict__ nb2,
                         const float* __restrict__ next_ew1,
                         unsigned short* nrec, unsigned short* __restrict__ Pc) {
    int n = blockIdx.x * blockDim.x + threadIdx.x;
    if (n >= NN) return;
    float o[16];
    ld_X16(nrec + (size_t)n*32, o);
    #pragma unroll
    for (int j = 0; j < 16; ++j) o[j] += agg[(size_t)n*16 + j];
    float h[16];
    #pragma unroll
    for (int j = 0; j < 16; ++j) {
        float a = nb1[j];
        #pragma unroll
        for (int i = 0; i < 16; ++i) a = fmaf(o[i], nw1[i*16+j], a);
        h[j] = fmaxf(a, 0.f);
    }
    float xn[16];
    #pragma unroll
    for (int j = 0; j < 16; ++j) {
        float a = nb2[j];
        #pragma unroll
        for (int i = 0; i < 16; ++i) a = fmaf(h[i], nw2[i*16+j], a);
        xn[j] = fmaxf(a, 0.f);
    }
    float pa[16], pc[16];
    #pragma unroll
    for (int j = 0; j < 16; ++j) {
        float sa = 0.f, sc = 0.f;
        #pragma unroll
        for (int i = 0; i < 16; ++i) {
            sa = fmaf(xn[i], next_ew1[i*16+j], sa);
            sc = fmaf(xn[i], next_ew1[(32+i)*16+j], sc);
        }
        pa[j] = sa; pc[j] = sc;
    }
    st_nrec16(nrec + (size_t)n*32, pa, xn);
    stbf16x16(Pc + (size_t)n*16, pc);
}

__global__ void node_last(const float* __restrict__ agg, const unsigned short* __restrict__ nrec,
                          const float* __restrict__ nw1, const float* __restrict__ nb1,
                          const float* __restrict__ nw2, const float* __restrict__ nb2,
                          const float* __restrict__ hw1, const float* __restrict__ hb1,
                          const float* __restrict__ hw2, const float* __restrict__ hb2,
                          float* __restrict__ out_n) {
    int n = blockIdx.x * blockDim.x + threadIdx.x;
    if (n >= NN) return;
    float o[16];
    ld_X16(nrec + (size_t)n*32, o);
    #pragma unroll
    for (int j = 0; j < 16; ++j) o[j] += agg[(size_t)n*16 + j];
    float h[16];
    #pragma unroll
    for (int j = 0; j < 16; ++j) {
        float a = nb1[j];
        #pragma unroll
        for (int i = 0; i < 16; ++i) a = fmaf(o[i], nw1[i*16+j], a);
        h[j] = fmaxf(a, 0.f);
    }
    float xn[16];
    #pragma unroll
    for (int j = 0; j < 16; ++j) {
        float a = nb2[j];
        #pragma unroll
        for (int i = 0; i < 16; ++i) a = fmaf(h[i], nw2[i*16+j], a);
        xn[j] = fmaxf(a, 0.f);
    }
    float g[16];
    #pragma unroll
    for (int j = 0; j < 16; ++j) {
        float a = hb1[j];
        #pragma unroll
        for (int i = 0; i < 16; ++i) a = fmaf(xn[i], hw1[i*16+j], a);
        g[j] = fmaxf(a, 0.f);
    }
    #pragma unroll
    for (int k = 0; k < 3; ++k) {
        float a = hb2[k];
        #pragma unroll
        for (int i = 0; i < 16; ++i) a = fmaf(g[i], hw2[i*3+k], a);
        out_n[(size_t)n*3 + k] = a;
    }
}

// ---- fused convs: one block per 128-node bucket, LDS-atomic aggT ----

// conv1: MLP from ea_s; msg3 into aggT; writeback agg dims 0..2.
__global__ void conv1E(const int* __restrict__ binbase,
                       const unsigned long long* __restrict__ srec,
                       const unsigned long long* __restrict__ ea_s,
                       const unsigned short* __restrict__ nrec, const unsigned short* __restrict__ Pcb,
                       const float* __restrict__ ew1, const float* __restrict__ eb1,
                       const float* __restrict__ ew2, const float* __restrict__ eb2,
                       unsigned short* __restrict__ ebuf, float* __restrict__ agg) {
    __shared__ float aggT[128 * 17];
    int bkt = blockIdx.x, tid = threadIdx.x;
    int n0 = bkt << BSHIFT;
    int base = binbase[bkt], end = binbase[bkt + 1];
    for (int i = tid; i < 128 * 17; i += 512) aggT[i] = 0.f;
    __syncthreads();
    for (int j = base + tid; j < end; j += 512) {
        unsigned long long sr = srec[j];
        int s = (int)(sr & 0x1FFFFu);
        int t = (int)((sr >> 17) & 0x1FFFFu);
        float pa[16], xv[16], pc[16];
        ld_nrec16(nrec + (size_t)s*32, pa, xv);
        ldbf16x16(Pcb + (size_t)t*16, pc);           // 4KB bucket window: L1-hit
        unsigned long long ew = ea_s[j];
        float e0 = bf2f((unsigned int)ew & 0xffffu);
        float e1 = bf2f(((unsigned int)ew >> 16) & 0xffffu);
        float e2 = bf2f((unsigned int)(ew >> 32) & 0xffffu);
        float h[16];
        #pragma unroll
        for (int jj = 0; jj < 16; ++jj) {
            float a = pa[jj] + pc[jj] + eb1[jj]
                    + e0*ew1[3*16+jj] + e1*ew1[4*16+jj] + e2*ew1[5*16+jj];
            h[jj] = fmaxf(a, 0.f);
        }
        float h2[16];
        #pragma unroll
        for (int jj = 0; jj < 16; ++jj) {
            float a = eb2[jj];
            #pragma unroll
            for (int i = 0; i < 16; ++i) a = fmaf(h[i], ew2[i*16+jj], a);
            h2[jj] = fmaxf(a, 0.f);
        }
        stbf16x16(ebuf + (size_t)j*16, h2);
        int loc = (t & LMASK) * 17;
        atomicAdd(&aggT[loc + 0], fmaxf(xv[0] + e0, 0.f));
        atomicAdd(&aggT[loc + 1], fmaxf(xv[1] + e1, 0.f));
        atomicAdd(&aggT[loc + 2], fmaxf(xv[2] + e2, 0.f));
    }
    __syncthreads();
    for (int i = tid; i < 128 * 3; i += 512) {
        int nl = i / 3, d = i - nl * 3;
        int node = n0 + nl;
        if (node < NN) agg[(size_t)node*16 + d] = aggT[nl*17 + d];
    }
}

// conv2/3: MLP from ebuf (in place); msg16 into aggT; full writeback.
__global__ void convE(const int* __restrict__ binbase,
                      const unsigned long long* __restrict__ srec,
                      unsigned short* ebuf,
                      const unsigned short* __restrict__ nrec, const unsigned short* __restrict__ Pcb,
                      const float* __restrict__ ew1, const float* __restrict__ eb1,
                      const float* __restrict__ ew2, const float* __restrict__ eb2,
                      float* __restrict__ agg) {
    __shared__ float aggT[128 * 17];
    int bkt = blockIdx.x, tid = threadIdx.x;
    int n0 = bkt << BSHIFT;
    int base = binbase[bkt], end = binbase[bkt + 1];
    for (int i = tid; i < 128 * 17; i += 512) aggT[i] = 0.f;
    __syncthreads();
    for (int j = base + tid; j < end; j += 512) {
        unsigned long long sr = srec[j];
        int s = (int)(sr & 0x1FFFFu);
        int t = (int)((sr >> 17) & 0x1FFFFu);
        float pa[16], xv[16], pc[16], ein[16];
        ld_nrec16(nrec + (size_t)s*32, pa, xv);      // one 64B line: Pa + X
        ldbf16x16(Pcb + (size_t)t*16, pc);           // 4KB bucket window: L1-hit
        ldbf16x16(ebuf + (size_t)j*16, ein);         // sequential stream
        float h[16];
        #pragma unroll
        for (int jj = 0; jj < 16; ++jj) h[jj] = pa[jj] + pc[jj] + eb1[jj];
        #pragma unroll
        for (int i = 0; i < 16; ++i) {
            #pragma unroll
            for (int jj = 0; jj < 16; ++jj) h[jj] = fmaf(ein[i], ew1[(16+i)*16+jj], h[jj]);
        }
        #pragma unroll
        for (int jj = 0; jj < 16; ++jj) h[jj] = fmaxf(h[jj], 0.f);
        float h2[16];
        #pragma unroll
        for (int jj = 0; jj < 16; ++jj) {
            float a = eb2[jj];
            #pragma unroll
            for (int i = 0; i < 16; ++i) a = fmaf(h[i], ew2[i*16+jj], a);
            h2[jj] = fmaxf(a, 0.f);
        }
        stbf16x16(ebuf + (size_t)j*16, h2);          // full 32B row, in place
        int loc = (t & LMASK) * 17;
        #pragma unroll
        for (int d = 0; d < 16; ++d)
            atomicAdd(&aggT[loc + d], fmaxf(xv[d] + ein[d], 0.f));
    }
    __syncthreads();
    for (int i = tid; i < 128 * 16; i += 512) {
        int nl = i >> 4, d = i & 15;
        int node = n0 + nl;
        if (node < NN) agg[(size_t)node*16 + d] = aggT[nl*17 + d];
    }
}

// conv3 edge head: stream ebuf3 + srec -> out_e scatter (after node_last).
__global__ void khead(const unsigned long long* __restrict__ srec,
                      const unsigned short* __restrict__ ebuf,
                      const float* __restrict__ hw1, const float* __restrict__ hb1,
                      const float* __restrict__ hw2, const float* __restrict__ hb2,
                      float* __restrict__ out_e) {
    int j = blockIdx.x * blockDim.x + threadIdx.x;
    if (j >= NE) return;
    unsigned long long sr = srec[j];
    int e = (int)(sr >> 34);
    float h2[16];
    ldbf16x16(ebuf + (size_t)j*16, h2);
    float g[16];
    #pragma unroll
    for (int jj = 0; jj < 16; ++jj) {
        float a = hb1[jj];
        #pragma unroll
        for (int i = 0; i < 16; ++i) a = fmaf(h2[i], hw1[i*16+jj], a);
        g[jj] = fmaxf(a, 0.f);
    }
    #pragma unroll
    for (int k = 0; k < 3; ++k) {
        float a = hb2[k];
        #pragma unroll
        for (int i = 0; i < 16; ++i) a = fmaf(g[i], hw2[i*3+k], a);
        out_e[(size_t)e*3 + k] = a;
    }
}

extern "C" void kernel_launch(void* const* d_in, const int* in_sizes, int n_in,
                              void* d_out, int out_size, void* d_ws, size_t ws_size,
                              hipStream_t stream) {
    const float* x  = (const float*)d_in[0];
    const float* ea = (const float*)d_in[1];
    const int*   ei = (const int*)d_in[2];
    const float *c1_ew1 = (const float*)d_in[3],  *c1_eb1 = (const float*)d_in[4];
    const float *c1_ew2 = (const float*)d_in[5],  *c1_eb2 = (const float*)d_in[6];
    const float *c1_nw1 = (const float*)d_in[7],  *c1_nb1 = (const float*)d_in[8];
    const float *c1_nw2 = (const float*)d_in[9],  *c1_nb2 = (const float*)d_in[10];
    const float *c2_ew1 = (const float*)d_in[11], *c2_eb1 = (const float*)d_in[12];
    const float *c2_ew2 = (const float*)d_in[13], *c2_eb2 = (const float*)d_in[14];
    const float *c2_nw1 = (const float*)d_in[15], *c2_nb1 = (const float*)d_in[16];
    const float *c2_nw2 = (const float*)d_in[17], *c2_nb2 = (const float*)d_in[18];
    const float *c3_ew1 = (const float*)d_in[19], *c3_eb1 = (const float*)d_in[20];
    const float *c3_ew2 = (const float*)d_in[21], *c3_eb2 = (const float*)d_in[22];
    const float *c3_nw1 = (const float*)d_in[23], *c3_nb1 = (const float*)d_in[24];
    const float *c3_nw2 = (const float*)d_in[25], *c3_nb2 = (const float*)d_in[26];
    const float *node_w1 = (const float*)d_in[27], *node_b1 = (const float*)d_in[28];
    const float *node_w2 = (const float*)d_in[29], *node_b2 = (const float*)d_in[30];
    const float *edge_w1 = (const float*)d_in[31], *edge_b1 = (const float*)d_in[32];
    const float *edge_w2 = (const float*)d_in[33], *edge_b2 = (const float*)d_in[34];

    // ---- ws carve-up (137.6 MB + 8 KB) ----
    char* w = (char*)d_ws;
    unsigned short* ebuf = (unsigned short*)w;          w += (size_t)NE * 32;   // 102.4 MB
    unsigned long long* srec = (unsigned long long*)w;  w += (size_t)NE * 8;    // 25.6 MB
    unsigned short* nrec = (unsigned short*)w;                                  // 6.4 MB
    int* hist = (int*)nrec;                             // 782*2048*4 = 6.406 MB alias
    w += (size_t)NN * 64;                               //   (over nrec+Pc head; dead
    unsigned short* Pc = (unsigned short*)w;            //    before prep1 runs)
    w += (size_t)NN * 32;                               // 3.2 MB
    int* binsum  = (int*)w;                             // NBKT
    int* binbase = binsum + NBKT;                       // NBKT+1

    // ---- d_out overlays ----
    float* out_n = (float*)d_out;
    float* out_e = out_n + (size_t)NN * 3;
    unsigned long long* ea_s = (unsigned long long*)out_e;       // NE*8 (dead after conv1E)
    float* agg = (float*)((char*)out_e + (size_t)NE * 8);        // N*16 f32

    const int B = 256;
    const int gn = (NN + B - 1) / B;                 // 391
    const int ge = NE / B;                           // 12500

    // ---- build (coarse bucket only; no kbucket) ----
    khist1<<<NBLK1, B, 0, stream>>>(ei, hist);
    kscan_a<<<NBKT, 1024, 0, stream>>>(hist, binsum);
    kscan_b<<<1, 1024, 0, stream>>>(binsum, binbase);
    kscatter1<<<NBLK1, B, 0, stream>>>(ei, ea, hist, binbase, srec, ea_s);

    // ---- conv1 (prep1 runs AFTER build: overwrites hist alias with nrec/Pc) ----
    prep1<<<gn, B, 0, stream>>>(x, c1_ew1, nrec, Pc);
    conv1E<<<NBKT, 512, 0, stream>>>(binbase, srec, ea_s, nrec, Pc,
                                     c1_ew1, c1_eb1, c1_ew2, c1_eb2, ebuf, agg);
    conv1_node<<<gn, B, 0, stream>>>(agg, x, c1_nw1, c1_nb1, c1_nw2, c1_nb2,
                                     c2_ew1, nrec, Pc);
    // ---- conv2 ----
    convE<<<NBKT, 512, 0, stream>>>(binbase, srec, ebuf, nrec, Pc,
                                    c2_ew1, c2_eb1, c2_ew2, c2_eb2, agg);
    node_mid<<<gn, B, 0, stream>>>(agg, c2_nw1, c2_nb1, c2_nw2, c2_nb2,
                                   c3_ew1, nrec, Pc);
    // ---- conv3 (agg consumed by node_last; khead then overwrites out_e) ----
    convE<<<NBKT, 512, 0, stream>>>(binbase, srec, ebuf, nrec, Pc,
                                    c3_ew1, c3_eb1, c3_ew2, c3_eb2, agg);
    node_last<<<gn, B, 0, stream>>>(agg, nrec, c3_nw1, c3_nb1, c3_nw2, c3_nb2,
                                    node_w1, node_b1, node_w2, node_b2, out_n);
    khead<<<ge, B, 0, stream>>>(srec, ebuf, edge_w1, edge_b1, edge_w2, edge_b2, out_e);
}

// Round 15
// 549.172 us; speedup vs baseline: 1.8837x; 1.8837x over previous
//
#include <hip/hip_runtime.h>
#include <hip/hip_bf16.h>

// GINE 3-conv GNN. Round-12/13 structure (best: 511us): two-level zero-global-
// atomic counting sort + slot-parallel fused convE (MLP + block-level segmented
// reduction) + separate khead. This round: ballot-based segment enumeration
// (3 barriers/block instead of 17, no Hillis-Steele) in conv1E/convE.
// N=100000, E=3200000 (=12500*256), H=16. fp32 in/out; edge_index int32.
//
// ws: ebuf[E][16]bf16 (102.4M; build scratch brec16 51.2M + hist 6.4M +
// binsum/binbase aliased inside, dead before conv1E); srec[E]u64 (25.6M);
// nrec[N][32]bf16 {Pa|X} (6.4M); Pc[N][16]bf16 (3.2M); [path A] agg (6.4M).
// out_e region overlays: ea_s[E]8B (dead after conv1E); [path B] agg.

#define NN 100000
#define NE 3200000
#define NBKT 782          // ceil(NN/128)
#define BSHIFT 7
#define LMASK 127
#define NBLK1 2048        // pass-1 blocks

__device__ __forceinline__ float bf2f(unsigned int h) {
    unsigned int u = h << 16;
    float f; __builtin_memcpy(&f, &u, 4); return f;
}
__device__ __forceinline__ unsigned short f2bf(float f) {
    unsigned int u; __builtin_memcpy(&u, &f, 4);
    u += 0x7fffu + ((u >> 16) & 1u);          // RNE
    return (unsigned short)(u >> 16);
}
__device__ __forceinline__ void unpk4(uint2 w, float* r) {
    r[0] = bf2f(w.x & 0xffffu); r[1] = bf2f(w.x >> 16);
    r[2] = bf2f(w.y & 0xffffu); r[3] = bf2f(w.y >> 16);
}
__device__ __forceinline__ void ldbf16x16(const unsigned short* p, float* r) {
    const uint4* q = reinterpret_cast<const uint4*>(p);
    uint4 a = q[0], b = q[1];
    unsigned int w[8] = {a.x, a.y, a.z, a.w, b.x, b.y, b.z, b.w};
    #pragma unroll
    for (int k = 0; k < 8; ++k) {
        r[2*k]   = bf2f(w[k] & 0xffffu);
        r[2*k+1] = bf2f(w[k] >> 16);
    }
}
__device__ __forceinline__ void stbf16x16(unsigned short* p, const float* r) {
    unsigned int w[8];
    #pragma unroll
    for (int k = 0; k < 8; ++k)
        w[k] = (unsigned int)f2bf(r[2*k]) | ((unsigned int)f2bf(r[2*k+1]) << 16);
    uint4* q = reinterpret_cast<uint4*>(p);
    q[0] = make_uint4(w[0], w[1], w[2], w[3]);
    q[1] = make_uint4(w[4], w[5], w[6], w[7]);
}
// nrec row: group g (dims 4g..4g+3): [g*8 .. g*8+3]=Pa, [g*8+4 .. g*8+7]=X
__device__ __forceinline__ void st_nrec16(unsigned short* p, const float* pa, const float* xv) {
    #pragma unroll
    for (int g = 0; g < 4; ++g) {
        uint4 w;
        w.x = (unsigned)f2bf(pa[4*g])   | ((unsigned)f2bf(pa[4*g+1]) << 16);
        w.y = (unsigned)f2bf(pa[4*g+2]) | ((unsigned)f2bf(pa[4*g+3]) << 16);
        w.z = (unsigned)f2bf(xv[4*g])   | ((unsigned)f2bf(xv[4*g+1]) << 16);
        w.w = (unsigned)f2bf(xv[4*g+2]) | ((unsigned)f2bf(xv[4*g+3]) << 16);
        *reinterpret_cast<uint4*>(p + g*8) = w;
    }
}
__device__ __forceinline__ void ld_nrec16(const unsigned short* p, float* pa, float* xv) {
    #pragma unroll
    for (int g = 0; g < 4; ++g) {
        uint4 w = *reinterpret_cast<const uint4*>(p + g*8);
        unpk4(make_uint2(w.x, w.y), pa + 4*g);
        unpk4(make_uint2(w.z, w.w), xv + 4*g);
    }
}
__device__ __forceinline__ void ld_X16(const unsigned short* p, float* xv) {
    #pragma unroll
    for (int g = 0; g < 4; ++g) {
        uint2 w = *reinterpret_cast<const uint2*>(p + g*8 + 4);
        unpk4(w, xv + 4*g);
    }
}

__global__ void kzero(float4* p, int n4) {
    int i = blockIdx.x * blockDim.x + threadIdx.x;
    if (i < n4) p[i] = make_float4(0.f, 0.f, 0.f, 0.f);
}

// ---------------- build: two-level counting sort (round-13 verbatim) ----------------

__global__ void khist1(const int* __restrict__ ei, int* __restrict__ hist) {
    __shared__ int h[NBKT];
    int blk = blockIdx.x, tid = threadIdx.x;
    for (int b = tid; b < NBKT; b += 256) h[b] = 0;
    __syncthreads();
    int e0 = (int)((long long)blk * NE / NBLK1);
    int e1 = (int)((long long)(blk + 1) * NE / NBLK1);
    for (int e = e0 + tid; e < e1; e += 256)
        atomicAdd(&h[ei[NE + e] >> BSHIFT], 1);     // LDS atomic
    __syncthreads();
    for (int b = tid; b < NBKT; b += 256) hist[b * NBLK1 + blk] = h[b];
}

__global__ void kscan_a(int* __restrict__ hist, int* __restrict__ binsum) {
    __shared__ int s[1024];
    int b = blockIdx.x, t = threadIdx.x;
    int base = b * NBLK1;
    int v0 = hist[base + t];
    s[t] = v0; __syncthreads();
    for (int off = 1; off < 1024; off <<= 1) {
        int u = (t >= off) ? s[t - off] : 0;
        __syncthreads();
        s[t] += u;
        __syncthreads();
    }
    int excl0 = s[t] - v0;
    int tot0 = s[1023];
    __syncthreads();
    int v1 = hist[base + 1024 + t];
    s[t] = v1; __syncthreads();
    for (int off = 1; off < 1024; off <<= 1) {
        int u = (t >= off) ? s[t - off] : 0;
        __syncthreads();
        s[t] += u;
        __syncthreads();
    }
    int excl1 = s[t] - v1 + tot0;
    hist[base + t] = excl0;
    hist[base + 1024 + t] = excl1;
    if (t == 1023) binsum[b] = s[1023] + tot0;
}

__global__ void kscan_b(const int* __restrict__ binsum, int* __restrict__ binbase) {
    __shared__ int s[1024];
    int t = threadIdx.x;
    int v = (t < NBKT) ? binsum[t] : 0;
    s[t] = v; __syncthreads();
    for (int off = 1; off < 1024; off <<= 1) {
        int u = (t >= off) ? s[t - off] : 0;
        __syncthreads();
        s[t] += u;
        __syncthreads();
    }
    if (t < NBKT) binbase[t] = s[t] - v;
    if (t == NBKT - 1) binbase[NBKT] = s[t];        // == NE
}

__global__ void kscatter1(const int* __restrict__ ei, const float* __restrict__ ea,
                          const int* __restrict__ hist, const int* __restrict__ binbase,
                          uint4* __restrict__ brec16) {
    __shared__ int cur[NBKT];
    int blk = blockIdx.x, tid = threadIdx.x;
    for (int b = tid; b < NBKT; b += 256)
        cur[b] = binbase[b] + hist[b * NBLK1 + blk];
    __syncthreads();
    int e0 = (int)((long long)blk * NE / NBLK1);
    int e1 = (int)((long long)(blk + 1) * NE / NBLK1);
    for (int e = e0 + tid; e < e1; e += 256) {
        int s = ei[e], d = ei[NE + e];
        float f0 = ea[(size_t)3*e], f1 = ea[(size_t)3*e+1], f2 = ea[(size_t)3*e+2];
        int pos = atomicAdd(&cur[d >> BSHIFT], 1);  // LDS atomic
        unsigned long long u = (unsigned long long)(unsigned int)s
                             | ((unsigned long long)(unsigned int)d << 17)
                             | ((unsigned long long)(unsigned int)e << 34);
        uint4 r;
        r.x = (unsigned int)u;
        r.y = (unsigned int)(u >> 32);
        r.z = (unsigned int)f2bf(f0) | ((unsigned int)f2bf(f1) << 16);
        r.w = (unsigned int)f2bf(f2);
        brec16[pos] = r;
    }
}

__global__ void kbucket(const uint4* __restrict__ brec16, const int* __restrict__ binbase,
                        unsigned long long* __restrict__ srec, unsigned int* __restrict__ ea_s) {
    __shared__ int cnt[128];
    __shared__ int off[128];
    __shared__ int cur[128];
    int bkt = blockIdx.x, t = threadIdx.x;
    int base = binbase[bkt], end = binbase[bkt + 1];
    if (t < 128) cnt[t] = 0;
    __syncthreads();
    for (int j = base + t; j < end; j += 256) {
        uint4 r = brec16[j];
        int dl = (int)(((r.x >> 17) | (r.y << 15)) & 0x1FFFFu) & LMASK;
        atomicAdd(&cnt[dl], 1);
    }
    __syncthreads();
    if (t < 128) { off[t] = cnt[t]; }
    __syncthreads();
    for (int o = 1; o < 128; o <<= 1) {
        int u = (t < 128 && t >= o) ? off[t - o] : 0;
        __syncthreads();
        if (t < 128) off[t] += u;
        __syncthreads();
    }
    if (t < 128) cur[t] = base + off[t] - cnt[t];
    __syncthreads();
    for (int j = base + t; j < end; j += 256) {
        uint4 r = brec16[j];
        int dl = (int)(((r.x >> 17) | (r.y << 15)) & 0x1FFFFu) & LMASK;
        int p = atomicAdd(&cur[dl], 1);
        srec[p] = (unsigned long long)r.x | ((unsigned long long)r.y << 32);
        *reinterpret_cast<uint2*>(&ea_s[(size_t)2*p]) = make_uint2(r.z, r.w);
    }
}

// ---------------- node-side kernels (verified, verbatim) ----------------

__global__ void prep1(const float* __restrict__ x, const float* __restrict__ ew1,
                      unsigned short* __restrict__ nrec, unsigned short* __restrict__ Pc) {
    int n = blockIdx.x * blockDim.x + threadIdx.x;
    if (n >= NN) return;
    float x0 = x[3*n], x1 = x[3*n+1], x2 = x[3*n+2];
    float pa[16], pc[16], xv[16];
    #pragma unroll
    for (int j = 0; j < 16; ++j) {
        pa[j] = x0*ew1[0*16+j] + x1*ew1[1*16+j] + x2*ew1[2*16+j];
        pc[j] = x0*ew1[6*16+j] + x1*ew1[7*16+j] + x2*ew1[8*16+j];
        xv[j] = 0.f;
    }
    xv[0] = x0; xv[1] = x1; xv[2] = x2;
    st_nrec16(nrec + (size_t)n*32, pa, xv);
    stbf16x16(Pc + (size_t)n*16, pc);
}

__global__ void conv1_node(const float* __restrict__ agg, const float* __restrict__ x,
                           const float* __restrict__ nw1, const float* __restrict__ nb1,
                           const float* __restrict__ nw2, const float* __restrict__ nb2,
                           const float* __restrict__ next_ew1,
                           unsigned short* __restrict__ nrec, unsigned short* __restrict__ Pc) {
    int n = blockIdx.x * blockDim.x + threadIdx.x;
    if (n >= NN) return;
    float o0 = agg[(size_t)n*16+0] + x[3*n];
    float o1 = agg[(size_t)n*16+1] + x[3*n+1];
    float o2 = agg[(size_t)n*16+2] + x[3*n+2];
    float h[16];
    #pragma unroll
    for (int j = 0; j < 16; ++j)
        h[j] = fmaxf(nb1[j] + o0*nw1[0*16+j] + o1*nw1[1*16+j] + o2*nw1[2*16+j], 0.f);
    float xn[16];
    #pragma unroll
    for (int j = 0; j < 16; ++j) {
        float a = nb2[j];
        #pragma unroll
        for (int i = 0; i < 16; ++i) a = fmaf(h[i], nw2[i*16+j], a);
        xn[j] = fmaxf(a, 0.f);
    }
    float pa[16], pc[16];
    #pragma unroll
    for (int j = 0; j < 16; ++j) {
        float sa = 0.f, sc = 0.f;
        #pragma unroll
        for (int i = 0; i < 16; ++i) {
            sa = fmaf(xn[i], next_ew1[i*16+j], sa);
            sc = fmaf(xn[i], next_ew1[(32+i)*16+j], sc);
        }
        pa[j] = sa; pc[j] = sc;
    }
    st_nrec16(nrec + (size_t)n*32, pa, xn);
    stbf16x16(Pc + (size_t)n*16, pc);
}

__global__ void node_mid(const float* __restrict__ agg,
                         const float* __restrict__ nw1, const float* __restrict__ nb1,
                         const float* __restrict__ nw2, const float* __restrict__ nb2,
                         const float* __restrict__ next_ew1,
                         unsigned short* nrec, unsigned short* __restrict__ Pc) {
    int n = blockIdx.x * blockDim.x + threadIdx.x;
    if (n >= NN) return;
    float o[16];
    ld_X16(nrec + (size_t)n*32, o);
    #pragma unroll
    for (int j = 0; j < 16; ++j) o[j] += agg[(size_t)n*16 + j];
    float h[16];
    #pragma unroll
    for (int j = 0; j < 16; ++j) {
        float a = nb1[j];
        #pragma unroll
        for (int i = 0; i < 16; ++i) a = fmaf(o[i], nw1[i*16+j], a);
        h[j] = fmaxf(a, 0.f);
    }
    float xn[16];
    #pragma unroll
    for (int j = 0; j < 16; ++j) {
        float a = nb2[j];
        #pragma unroll
        for (int i = 0; i < 16; ++i) a = fmaf(h[i], nw2[i*16+j], a);
        xn[j] = fmaxf(a, 0.f);
    }
    float pa[16], pc[16];
    #pragma unroll
    for (int j = 0; j < 16; ++j) {
        float sa = 0.f, sc = 0.f;
        #pragma unroll
        for (int i = 0; i < 16; ++i) {
            sa = fmaf(xn[i], next_ew1[i*16+j], sa);
            sc = fmaf(xn[i], next_ew1[(32+i)*16+j], sc);
        }
        pa[j] = sa; pc[j] = sc;
    }
    st_nrec16(nrec + (size_t)n*32, pa, xn);
    stbf16x16(Pc + (size_t)n*16, pc);
}

__global__ void node_last(const float* __restrict__ agg, const unsigned short* __restrict__ nrec,
                          const float* __restrict__ nw1, const float* __restrict__ nb1,
                          const float* __restrict__ nw2, const float* __restrict__ nb2,
                          const float* __restrict__ hw1, const float* __restrict__ hb1,
                          const float* __restrict__ hw2, const float* __restrict__ hb2,
                          float* __restrict__ out_n) {
    int n = blockIdx.x * blockDim.x + threadIdx.x;
    if (n >= NN) return;
    float o[16];
    ld_X16(nrec + (size_t)n*32, o);
    #pragma unroll
    for (int j = 0; j < 16; ++j) o[j] += agg[(size_t)n*16 + j];
    float h[16];
    #pragma unroll
    for (int j = 0; j < 16; ++j) {
        float a = nb1[j];
        #pragma unroll
        for (int i = 0; i < 16; ++i) a = fmaf(o[i], nw1[i*16+j], a);
        h[j] = fmaxf(a, 0.f);
    }
    float xn[16];
    #pragma unroll
    for (int j = 0; j < 16; ++j) {
        float a = nb2[j];
        #pragma unroll
        for (int i = 0; i < 16; ++i) a = fmaf(h[i], nw2[i*16+j], a);
        xn[j] = fmaxf(a, 0.f);
    }
    float g[16];
    #pragma unroll
    for (int j = 0; j < 16; ++j) {
        float a = hb1[j];
        #pragma unroll
        for (int i = 0; i < 16; ++i) a = fmaf(xn[i], hw1[i*16+j], a);
        g[j] = fmaxf(a, 0.f);
    }
    #pragma unroll
    for (int k = 0; k < 3; ++k) {
        float a = hb2[k];
        #pragma unroll
        for (int i = 0; i < 16; ++i) a = fmaf(g[i], hw2[i*3+k], a);
        out_n[(size_t)n*3 + k] = a;
    }
}

// ---- fused convs: slot-parallel MLP + ballot-enumerated segmented reduction ----

__global__ void conv1E(const unsigned long long* __restrict__ srec,
                       const unsigned int* __restrict__ ea_s,
                       const unsigned short* __restrict__ nrec, const unsigned short* __restrict__ Pcb,
                       const float* __restrict__ ew1, const float* __restrict__ eb1,
                       const float* __restrict__ ew2, const float* __restrict__ eb2,
                       unsigned short* __restrict__ ebuf, float* agg) {
    __shared__ float smsg[256 * 5];
    __shared__ int st_[256];
    __shared__ int segofs[257];
    __shared__ int wtot[4];
    int tid = threadIdx.x;
    int j = blockIdx.x * 256 + tid;
    unsigned long long sr = srec[j];
    int s = (int)(sr & 0x1FFFFu);
    int t = (int)((sr >> 17) & 0x1FFFFu);
    float pa[16], xv[16], pc[16];
    ld_nrec16(nrec + (size_t)s*32, pa, xv);
    ldbf16x16(Pcb + (size_t)t*16, pc);
    uint2 eaw = *reinterpret_cast<const uint2*>(&ea_s[(size_t)2*j]);
    float e0 = bf2f(eaw.x & 0xffffu), e1 = bf2f(eaw.x >> 16), e2 = bf2f(eaw.y & 0xffffu);
    float h[16];
    #pragma unroll
    for (int jj = 0; jj < 16; ++jj) {
        float a = pa[jj] + pc[jj] + eb1[jj]
                + e0*ew1[3*16+jj] + e1*ew1[4*16+jj] + e2*ew1[5*16+jj];
        h[jj] = fmaxf(a, 0.f);
    }
    float h2[16];
    #pragma unroll
    for (int jj = 0; jj < 16; ++jj) {
        float a = eb2[jj];
        #pragma unroll
        for (int i = 0; i < 16; ++i) a = fmaf(h[i], ew2[i*16+jj], a);
        h2[jj] = fmaxf(a, 0.f);
    }
    stbf16x16(ebuf + (size_t)j*16, h2);
    st_[tid] = t;
    smsg[tid*5 + 0] = fmaxf(xv[0] + e0, 0.f);
    smsg[tid*5 + 1] = fmaxf(xv[1] + e1, 0.f);
    smsg[tid*5 + 2] = fmaxf(xv[2] + e2, 0.f);
    __syncthreads();
    int flag = (tid == 0 || st_[tid-1] != t) ? 1 : 0;
    unsigned long long mask = __ballot(flag);
    int lane = tid & 63, wid = tid >> 6;
    if (lane == 0) wtot[wid] = __popcll(mask);
    __syncthreads();
    int wofs = 0;
    #pragma unroll
    for (int k = 0; k < 4; ++k) if (k < wid) wofs += wtot[k];
    int nseg = wtot[0] + wtot[1] + wtot[2] + wtot[3];
    if (flag) segofs[wofs + __popcll(mask & ((1ull << lane) - 1ull))] = tid;
    if (tid == 0) segofs[nseg] = 256;
    __syncthreads();
    for (int p = tid; p < nseg * 4; p += 256) {
        int seg = p >> 2, d = p & 3;
        if (d == 3) continue;
        int k0 = segofs[seg], k1 = segofs[seg + 1];
        float a = 0.f;
        for (int k = k0; k < k1; ++k) a += smsg[k*5 + d];
        int node = st_[k0];
        if (seg == 0 || seg == nseg - 1)
            atomicAdd(&agg[(size_t)node*16 + d], a);
        else
            agg[(size_t)node*16 + d] = a;
    }
}

// conv2/3: MLP from ebuf (in place); msg16; segmented reduction -> agg.
__global__ void convE(const unsigned long long* __restrict__ srec,
                      unsigned short* ebuf,
                      const unsigned short* __restrict__ nrec, const unsigned short* __restrict__ Pcb,
                      const float* __restrict__ ew1, const float* __restrict__ eb1,
                      const float* __restrict__ ew2, const float* __restrict__ eb2,
                      float* agg) {
    __shared__ float smsg[256 * 17];
    __shared__ int st_[256];
    __shared__ int segofs[257];
    __shared__ int wtot[4];
    int tid = threadIdx.x;
    int j = blockIdx.x * 256 + tid;
    unsigned long long sr = srec[j];
    int s = (int)(sr & 0x1FFFFu);
    int t = (int)((sr >> 17) & 0x1FFFFu);
    float pa[16], xv[16], pc[16], ein[16];
    ld_nrec16(nrec + (size_t)s*32, pa, xv);      // one 64B line: Pa + X
    ldbf16x16(Pcb + (size_t)t*16, pc);           // dst-grouped, cached
    ldbf16x16(ebuf + (size_t)j*16, ein);         // sequential stream
    float h[16];
    #pragma unroll
    for (int jj = 0; jj < 16; ++jj) h[jj] = pa[jj] + pc[jj] + eb1[jj];
    #pragma unroll
    for (int i = 0; i < 16; ++i) {
        #pragma unroll
        for (int jj = 0; jj < 16; ++jj) h[jj] = fmaf(ein[i], ew1[(16+i)*16+jj], h[jj]);
    }
    #pragma unroll
    for (int jj = 0; jj < 16; ++jj) h[jj] = fmaxf(h[jj], 0.f);
    float h2[16];
    #pragma unroll
    for (int jj = 0; jj < 16; ++jj) {
        float a = eb2[jj];
        #pragma unroll
        for (int i = 0; i < 16; ++i) a = fmaf(h[i], ew2[i*16+jj], a);
        h2[jj] = fmaxf(a, 0.f);
    }
    stbf16x16(ebuf + (size_t)j*16, h2);          // full 32B row, in place
    st_[tid] = t;
    #pragma unroll
    for (int d = 0; d < 16; ++d) smsg[tid*17 + d] = fmaxf(xv[d] + ein[d], 0.f);
    __syncthreads();
    int flag = (tid == 0 || st_[tid-1] != t) ? 1 : 0;
    unsigned long long mask = __ballot(flag);
    int lane = tid & 63, wid = tid >> 6;
    if (lane == 0) wtot[wid] = __popcll(mask);
    __syncthreads();
    int wofs = 0;
    #pragma unroll
    for (int k = 0; k < 4; ++k) if (k < wid) wofs += wtot[k];
    int nseg = wtot[0] + wtot[1] + wtot[2] + wtot[3];
    if (flag) segofs[wofs + __popcll(mask & ((1ull << lane) - 1ull))] = tid;
    if (tid == 0) segofs[nseg] = 256;
    __syncthreads();
    for (int p = tid; p < nseg * 16; p += 256) {
        int seg = p >> 4, d = p & 15;
        int k0 = segofs[seg], k1 = segofs[seg + 1];
        float a = 0.f;
        for (int k = k0; k < k1; ++k) a += smsg[k*17 + d];
        int node = st_[k0];
        if (seg == 0 || seg == nseg - 1)
            atomicAdd(&agg[(size_t)node*16 + d], a);   // boundary: <=2 segs/block
        else
            agg[(size_t)node*16 + d] = a;              // interior: plain store
    }
}

// conv3 edge head: stream ebuf3 + srec -> out_e scatter (after node_last).
__global__ void khead(const unsigned long long* __restrict__ srec,
                      const unsigned short* __restrict__ ebuf,
                      const float* __restrict__ hw1, const float* __restrict__ hb1,
                      const float* __restrict__ hw2, const float* __restrict__ hb2,
                      float* __restrict__ out_e) {
    int j = blockIdx.x * blockDim.x + threadIdx.x;
    if (j >= NE) return;
    unsigned long long sr = srec[j];
    int e = (int)(sr >> 34);
    float h2[16];
    ldbf16x16(ebuf + (size_t)j*16, h2);
    float g[16];
    #pragma unroll
    for (int jj = 0; jj < 16; ++jj) {
        float a = hb1[jj];
        #pragma unroll
        for (int i = 0; i < 16; ++i) a = fmaf(h2[i], hw1[i*16+jj], a);
        g[jj] = fmaxf(a, 0.f);
    }
    #pragma unroll
    for (int k = 0; k < 3; ++k) {
        float a = hb2[k];
        #pragma unroll
        for (int i = 0; i < 16; ++i) a = fmaf(g[i], hw2[i*3+k], a);
        out_e[(size_t)e*3 + k] = a;
    }
}

extern "C" void kernel_launch(void* const* d_in, const int* in_sizes, int n_in,
                              void* d_out, int out_size, void* d_ws, size_t ws_size,
                              hipStream_t stream) {
    const float* x  = (const float*)d_in[0];
    const float* ea = (const float*)d_in[1];
    const int*   ei = (const int*)d_in[2];
    const float *c1_ew1 = (const float*)d_in[3],  *c1_eb1 = (const float*)d_in[4];
    const float *c1_ew2 = (const float*)d_in[5],  *c1_eb2 = (const float*)d_in[6];
    const float *c1_nw1 = (const float*)d_in[7],  *c1_nb1 = (const float*)d_in[8];
    const float *c1_nw2 = (const float*)d_in[9],  *c1_nb2 = (const float*)d_in[10];
    const float *c2_ew1 = (const float*)d_in[11], *c2_eb1 = (const float*)d_in[12];
    const float *c2_ew2 = (const float*)d_in[13], *c2_eb2 = (const float*)d_in[14];
    const float *c2_nw1 = (const float*)d_in[15], *c2_nb1 = (const float*)d_in[16];
    const float *c2_nw2 = (const float*)d_in[17], *c2_nb2 = (const float*)d_in[18];
    const float *c3_ew1 = (const float*)d_in[19], *c3_eb1 = (const float*)d_in[20];
    const float *c3_ew2 = (const float*)d_in[21], *c3_eb2 = (const float*)d_in[22];
    const float *c3_nw1 = (const float*)d_in[23], *c3_nb1 = (const float*)d_in[24];
    const float *c3_nw2 = (const float*)d_in[25], *c3_nb2 = (const float*)d_in[26];
    const float *node_w1 = (const float*)d_in[27], *node_b1 = (const float*)d_in[28];
    const float *node_w2 = (const float*)d_in[29], *node_b2 = (const float*)d_in[30];
    const float *edge_w1 = (const float*)d_in[31], *edge_b1 = (const float*)d_in[32];
    const float *edge_w2 = (const float*)d_in[33], *edge_b2 = (const float*)d_in[34];

    // ---- ws carve-up ----
    char* w = (char*)d_ws;
    unsigned short* ebuf = (unsigned short*)w;               // NE*32; build scratch aliases inside:
    uint4* brec16 = (uint4*)w;                               //   NE*16 = 51.2 MB
    int* hist   = (int*)(w + (size_t)NE*16);                 //   NBKT*NBLK1*4 = 6.4 MB
    int* binsum = hist + NBKT * NBLK1;
    int* binbase = binsum + NBKT;
    w += (size_t)NE * 32;
    unsigned long long* srec = (unsigned long long*)w;  w += (size_t)NE * 8;   // 25.6 MB
    unsigned short* nrec = (unsigned short*)w;          w += (size_t)NN * 64;  // 6.4 MB
    unsigned short* Pc   = (unsigned short*)w;          w += (size_t)NN * 32;  // 3.2 MB

    // ---- d_out overlays ----
    float* out_n = (float*)d_out;
    float* out_e = out_n + (size_t)NN * 3;
    unsigned int* ea_s = (unsigned int*)out_e;         // NE*8 (dead after conv1E)

    // agg: ws if it fits, else out_e tail (both proven)
    const size_t NEED_A = (size_t)NE*32 + (size_t)NE*8 + (size_t)NN*64 + (size_t)NN*32
                        + (size_t)NN*64 + 1024;
    bool bigws = (ws_size >= NEED_A);
    float* agg = bigws ? (float*)w
                       : (float*)((char*)out_e + (size_t)NE * 8);

    const int B = 256;
    const int gn = (NN + B - 1) / B;                 // 391
    const int ge = NE / B;                           // 12500 exact
    const int gz = (NN * 16 / 4 + B - 1) / B;        // 1563

    // ---- build (no global atomics) ----
    khist1<<<NBLK1, B, 0, stream>>>(ei, hist);
    kscan_a<<<NBKT, 1024, 0, stream>>>(hist, binsum);
    kscan_b<<<1, 1024, 0, stream>>>(binsum, binbase);
    kscatter1<<<NBLK1, B, 0, stream>>>(ei, ea, hist, binbase, brec16);
    kbucket<<<NBKT, B, 0, stream>>>(brec16, binbase, srec, ea_s);

    // ---- conv1 (conv1E clobbers brec16/hist region via ebuf — all dead) ----
    prep1<<<gn, B, 0, stream>>>(x, c1_ew1, nrec, Pc);
    kzero<<<gz, B, 0, stream>>>((float4*)agg, NN * 16 / 4);
    conv1E<<<ge, B, 0, stream>>>(srec, ea_s, nrec, Pc,
                                 c1_ew1, c1_eb1, c1_ew2, c1_eb2, ebuf, agg);
    conv1_node<<<gn, B, 0, stream>>>(agg, x, c1_nw1, c1_nb1, c1_nw2, c1_nb2,
                                     c2_ew1, nrec, Pc);
    // ---- conv2 ----
    kzero<<<gz, B, 0, stream>>>((float4*)agg, NN * 16 / 4);
    convE<<<ge, B, 0, stream>>>(srec, ebuf, nrec, Pc,
                                c2_ew1, c2_eb1, c2_ew2, c2_eb2, agg);
    node_mid<<<gn, B, 0, stream>>>(agg, c2_nw1, c2_nb1, c2_nw2, c2_nb2,
                                   c3_ew1, nrec, Pc);
    // ---- conv3 (agg consumed by node_last; khead then overwrites out_e) ----
    kzero<<<gz, B, 0, stream>>>((float4*)agg, NN * 16 / 4);
    convE<<<ge, B, 0, stream>>>(srec, ebuf, nrec, Pc,
                                c3_ew1, c3_eb1, c3_ew2, c3_eb2, agg);
    node_last<<<gn, B, 0, stream>>>(agg, nrec, c3_nw1, c3_nb1, c3_nw2, c3_nb2,
                                    node_w1, node_b1, node_w2, node_b2, out_n);
    khead<<<ge, B, 0, stream>>>(srec, ebuf, edge_w1, edge_b1, edge_w2, edge_b2, out_e);
}

// Round 16
// 511.970 us; speedup vs baseline: 2.0205x; 1.0727x over previous
//
#include <hip/hip_runtime.h>
#include <hip/hip_bf16.h>

// GINE 3-conv GNN. Round-12 configuration (best measured: 511us), resubmitted
// verbatim. Zero-global-atomic two-level counting sort build + slot-parallel
// FUSED conv kernels with contention-free block-level segmented reduction:
//   convE: 1 thread/slot (256/block, slot-major). Phase 1: full edge MLP in
//   registers, nrec 64B line gives Pa+X in one gather, msg -> padded LDS tile.
//   Phase 2: segment heads flagged by neighbor-t compare, Hillis-Steele
//   enumerate, (seg,d) threads sum segments; interior segs plain-store agg,
//   boundary segs (<=2/block) atomicAdd into pre-zeroed agg.
// N=100000, E=3200000 (= 12500*256 exactly), H=16. fp32 in/out.
//
// ws (137.6 MB): ebuf[E][16]bf16 (build scratch brec16/hist/binsum/binbase
// aliased inside, dead before conv1); srec[E]u64; nrec[N][32]bf16 {Pa|X};
// Pc[N][16]bf16. out_n region: start[N+1] (unused after build; dead anyway).
// out_e region: ea_s[E]8B + agg[N][16]f32 (dead before khead writes out_e).

#define NN 100000
#define NE 3200000
#define NBKT 782          // ceil(NN/128)
#define BSHIFT 7
#define LMASK 127
#define NBLK1 1024        // pass-1 blocks
#define EPB1 3125         // NE / NBLK1 (exact)

__device__ __forceinline__ float bf2f(unsigned int h) {
    unsigned int u = h << 16;
    float f; __builtin_memcpy(&f, &u, 4); return f;
}
__device__ __forceinline__ unsigned short f2bf(float f) {
    unsigned int u; __builtin_memcpy(&u, &f, 4);
    u += 0x7fffu + ((u >> 16) & 1u);          // RNE
    return (unsigned short)(u >> 16);
}
__device__ __forceinline__ void unpk4(uint2 w, float* r) {
    r[0] = bf2f(w.x & 0xffffu); r[1] = bf2f(w.x >> 16);
    r[2] = bf2f(w.y & 0xffffu); r[3] = bf2f(w.y >> 16);
}
__device__ __forceinline__ void ldbf16x16(const unsigned short* p, float* r) {
    const uint4* q = reinterpret_cast<const uint4*>(p);
    uint4 a = q[0], b = q[1];
    unsigned int w[8] = {a.x, a.y, a.z, a.w, b.x, b.y, b.z, b.w};
    #pragma unroll
    for (int k = 0; k < 8; ++k) {
        r[2*k]   = bf2f(w[k] & 0xffffu);
        r[2*k+1] = bf2f(w[k] >> 16);
    }
}
__device__ __forceinline__ void stbf16x16(unsigned short* p, const float* r) {
    unsigned int w[8];
    #pragma unroll
    for (int k = 0; k < 8; ++k)
        w[k] = (unsigned int)f2bf(r[2*k]) | ((unsigned int)f2bf(r[2*k+1]) << 16);
    uint4* q = reinterpret_cast<uint4*>(p);
    q[0] = make_uint4(w[0], w[1], w[2], w[3]);
    q[1] = make_uint4(w[4], w[5], w[6], w[7]);
}
// nrec row: group g (dims 4g..4g+3): [g*8 .. g*8+3]=Pa, [g*8+4 .. g*8+7]=X
__device__ __forceinline__ void st_nrec16(unsigned short* p, const float* pa, const float* xv) {
    #pragma unroll
    for (int g = 0; g < 4; ++g) {
        uint4 w;
        w.x = (unsigned)f2bf(pa[4*g])   | ((unsigned)f2bf(pa[4*g+1]) << 16);
        w.y = (unsigned)f2bf(pa[4*g+2]) | ((unsigned)f2bf(pa[4*g+3]) << 16);
        w.z = (unsigned)f2bf(xv[4*g])   | ((unsigned)f2bf(xv[4*g+1]) << 16);
        w.w = (unsigned)f2bf(xv[4*g+2]) | ((unsigned)f2bf(xv[4*g+3]) << 16);
        *reinterpret_cast<uint4*>(p + g*8) = w;
    }
}
__device__ __forceinline__ void ld_nrec16(const unsigned short* p, float* pa, float* xv) {
    #pragma unroll
    for (int g = 0; g < 4; ++g) {
        uint4 w = *reinterpret_cast<const uint4*>(p + g*8);
        unpk4(make_uint2(w.x, w.y), pa + 4*g);
        unpk4(make_uint2(w.z, w.w), xv + 4*g);
    }
}
__device__ __forceinline__ void ld_X16(const unsigned short* p, float* xv) {
    #pragma unroll
    for (int g = 0; g < 4; ++g) {
        uint2 w = *reinterpret_cast<const uint2*>(p + g*8 + 4);
        unpk4(w, xv + 4*g);
    }
}

__global__ void kzero(float4* p, int n4) {
    int i = blockIdx.x * blockDim.x + threadIdx.x;
    if (i < n4) p[i] = make_float4(0.f, 0.f, 0.f, 0.f);
}

// ---------------- build: two-level counting sort (no global atomics) ----------------

__global__ void khist1(const int* __restrict__ ei, int* __restrict__ hist) {
    __shared__ int h[NBKT];
    int blk = blockIdx.x, tid = threadIdx.x;
    for (int b = tid; b < NBKT; b += 256) h[b] = 0;
    __syncthreads();
    int e0 = blk * EPB1;
    for (int e = e0 + tid; e < e0 + EPB1; e += 256)
        atomicAdd(&h[ei[NE + e] >> BSHIFT], 1);     // LDS atomic
    __syncthreads();
    for (int b = tid; b < NBKT; b += 256) hist[b * NBLK1 + blk] = h[b];
}

__global__ void kscan_a(int* __restrict__ hist, int* __restrict__ binsum) {
    __shared__ int s[NBLK1];
    int b = blockIdx.x, t = threadIdx.x;
    int v = hist[b * NBLK1 + t];
    s[t] = v; __syncthreads();
    for (int off = 1; off < NBLK1; off <<= 1) {
        int u = (t >= off) ? s[t - off] : 0;
        __syncthreads();
        s[t] += u;
        __syncthreads();
    }
    hist[b * NBLK1 + t] = s[t] - v;                 // exclusive within bin
    if (t == NBLK1 - 1) binsum[b] = s[t];
}

__global__ void kscan_b(const int* __restrict__ binsum, int* __restrict__ binbase,
                        int* __restrict__ start) {
    __shared__ int s[1024];
    int t = threadIdx.x;
    int v = (t < NBKT) ? binsum[t] : 0;
    s[t] = v; __syncthreads();
    for (int off = 1; off < 1024; off <<= 1) {
        int u = (t >= off) ? s[t - off] : 0;
        __syncthreads();
        s[t] += u;
        __syncthreads();
    }
    if (t < NBKT) binbase[t] = s[t] - v;
    if (t == NBKT - 1) binbase[NBKT] = s[t];        // == NE
    if (t == 0) start[NN] = NE;
}

__global__ void kscatter1(const int* __restrict__ ei, const float* __restrict__ ea,
                          const int* __restrict__ hist, const int* __restrict__ binbase,
                          uint4* __restrict__ brec16) {
    __shared__ int cur[NBKT];
    int blk = blockIdx.x, tid = threadIdx.x;
    for (int b = tid; b < NBKT; b += 256)
        cur[b] = binbase[b] + hist[b * NBLK1 + blk];
    __syncthreads();
    int e0 = blk * EPB1;
    for (int e = e0 + tid; e < e0 + EPB1; e += 256) {
        int s = ei[e], d = ei[NE + e];
        float f0 = ea[(size_t)3*e], f1 = ea[(size_t)3*e+1], f2 = ea[(size_t)3*e+2];
        int pos = atomicAdd(&cur[d >> BSHIFT], 1);  // LDS atomic
        unsigned long long u = (unsigned long long)(unsigned int)s
                             | ((unsigned long long)(unsigned int)d << 17)
                             | ((unsigned long long)(unsigned int)e << 34);
        uint4 r;
        r.x = (unsigned int)u;
        r.y = (unsigned int)(u >> 32);
        r.z = (unsigned int)f2bf(f0) | ((unsigned int)f2bf(f1) << 16);
        r.w = (unsigned int)f2bf(f2);
        brec16[pos] = r;
    }
}

__global__ void kbucket(const uint4* __restrict__ brec16, const int* __restrict__ binbase,
                        unsigned long long* __restrict__ srec, unsigned int* __restrict__ ea_s,
                        int* __restrict__ start) {
    __shared__ int cnt[128];
    __shared__ int off[128];
    __shared__ int cur[128];
    int bkt = blockIdx.x, t = threadIdx.x;
    int base = binbase[bkt], end = binbase[bkt + 1];
    if (t < 128) cnt[t] = 0;
    __syncthreads();
    for (int j = base + t; j < end; j += 256) {
        uint4 r = brec16[j];
        int dl = (int)(((r.x >> 17) | (r.y << 15)) & 0x1FFFFu) & LMASK;
        atomicAdd(&cnt[dl], 1);
    }
    __syncthreads();
    if (t < 128) { off[t] = cnt[t]; }
    __syncthreads();
    for (int o = 1; o < 128; o <<= 1) {
        int u = (t < 128 && t >= o) ? off[t - o] : 0;
        __syncthreads();
        if (t < 128) off[t] += u;
        __syncthreads();
    }
    if (t < 128) {
        int excl = off[t] - cnt[t];
        int node = bkt * 128 + t;
        if (node < NN) start[node] = base + excl;
        cur[t] = base + excl;
    }
    __syncthreads();
    for (int j = base + t; j < end; j += 256) {
        uint4 r = brec16[j];
        int dl = (int)(((r.x >> 17) | (r.y << 15)) & 0x1FFFFu) & LMASK;
        int p = atomicAdd(&cur[dl], 1);
        srec[p] = (unsigned long long)r.x | ((unsigned long long)r.y << 32);
        *reinterpret_cast<uint2*>(&ea_s[(size_t)2*p]) = make_uint2(r.z, r.w);
    }
}

// ---------------- node-side kernels (verified, verbatim) ----------------

__global__ void prep1(const float* __restrict__ x, const float* __restrict__ ew1,
                      unsigned short* __restrict__ nrec, unsigned short* __restrict__ Pc) {
    int n = blockIdx.x * blockDim.x + threadIdx.x;
    if (n >= NN) return;
    float x0 = x[3*n], x1 = x[3*n+1], x2 = x[3*n+2];
    float pa[16], pc[16], xv[16];
    #pragma unroll
    for (int j = 0; j < 16; ++j) {
        pa[j] = x0*ew1[0*16+j] + x1*ew1[1*16+j] + x2*ew1[2*16+j];
        pc[j] = x0*ew1[6*16+j] + x1*ew1[7*16+j] + x2*ew1[8*16+j];
        xv[j] = 0.f;
    }
    xv[0] = x0; xv[1] = x1; xv[2] = x2;
    st_nrec16(nrec + (size_t)n*32, pa, xv);
    stbf16x16(Pc + (size_t)n*16, pc);
}

__global__ void conv1_node(const float* __restrict__ agg, const float* __restrict__ x,
                           const float* __restrict__ nw1, const float* __restrict__ nb1,
                           const float* __restrict__ nw2, const float* __restrict__ nb2,
                           const float* __restrict__ next_ew1,
                           unsigned short* __restrict__ nrec, unsigned short* __restrict__ Pc) {
    int n = blockIdx.x * blockDim.x + threadIdx.x;
    if (n >= NN) return;
    float o0 = agg[(size_t)n*16+0] + x[3*n];
    float o1 = agg[(size_t)n*16+1] + x[3*n+1];
    float o2 = agg[(size_t)n*16+2] + x[3*n+2];
    float h[16];
    #pragma unroll
    for (int j = 0; j < 16; ++j)
        h[j] = fmaxf(nb1[j] + o0*nw1[0*16+j] + o1*nw1[1*16+j] + o2*nw1[2*16+j], 0.f);
    float xn[16];
    #pragma unroll
    for (int j = 0; j < 16; ++j) {
        float a = nb2[j];
        #pragma unroll
        for (int i = 0; i < 16; ++i) a = fmaf(h[i], nw2[i*16+j], a);
        xn[j] = fmaxf(a, 0.f);
    }
    float pa[16], pc[16];
    #pragma unroll
    for (int j = 0; j < 16; ++j) {
        float sa = 0.f, sc = 0.f;
        #pragma unroll
        for (int i = 0; i < 16; ++i) {
            sa = fmaf(xn[i], next_ew1[i*16+j], sa);
            sc = fmaf(xn[i], next_ew1[(32+i)*16+j], sc);
        }
        pa[j] = sa; pc[j] = sc;
    }
    st_nrec16(nrec + (size_t)n*32, pa, xn);
    stbf16x16(Pc + (size_t)n*16, pc);
}

__global__ void node_mid(const float* __restrict__ agg,
                         const float* __restrict__ nw1, const float* __restrict__ nb1,
                         const float* __restrict__ nw2, const float* __restrict__ nb2,
                         const float* __restrict__ next_ew1,
                         unsigned short* nrec, unsigned short* __restrict__ Pc) {
    int n = blockIdx.x * blockDim.x + threadIdx.x;
    if (n >= NN) return;
    float o[16];
    ld_X16(nrec + (size_t)n*32, o);
    #pragma unroll
    for (int j = 0; j < 16; ++j) o[j] += agg[(size_t)n*16 + j];
    float h[16];
    #pragma unroll
    for (int j = 0; j < 16; ++j) {
        float a = nb1[j];
        #pragma unroll
        for (int i = 0; i < 16; ++i) a = fmaf(o[i], nw1[i*16+j], a);
        h[j] = fmaxf(a, 0.f);
    }
    float xn[16];
    #pragma unroll
    for (int j = 0; j < 16; ++j) {
        float a = nb2[j];
        #pragma unroll
        for (int i = 0; i < 16; ++i) a = fmaf(h[i], nw2[i*16+j], a);
        xn[j] = fmaxf(a, 0.f);
    }
    float pa[16], pc[16];
    #pragma unroll
    for (int j = 0; j < 16; ++j) {
        float sa = 0.f, sc = 0.f;
        #pragma unroll
        for (int i = 0; i < 16; ++i) {
            sa = fmaf(xn[i], next_ew1[i*16+j], sa);
            sc = fmaf(xn[i], next_ew1[(32+i)*16+j], sc);
        }
        pa[j] = sa; pc[j] = sc;
    }
    st_nrec16(nrec + (size_t)n*32, pa, xn);
    stbf16x16(Pc + (size_t)n*16, pc);
}

__global__ void node_last(const float* __restrict__ agg, const unsigned short* __restrict__ nrec,
                          const float* __restrict__ nw1, const float* __restrict__ nb1,
                          const float* __restrict__ nw2, const float* __restrict__ nb2,
                          const float* __restrict__ hw1, const float* __restrict__ hb1,
                          const float* __restrict__ hw2, const float* __restrict__ hb2,
                          float* __restrict__ out_n) {
    int n = blockIdx.x * blockDim.x + threadIdx.x;
    if (n >= NN) return;
    float o[16];
    ld_X16(nrec + (size_t)n*32, o);
    #pragma unroll
    for (int j = 0; j < 16; ++j) o[j] += agg[(size_t)n*16 + j];
    float h[16];
    #pragma unroll
    for (int j = 0; j < 16; ++j) {
        float a = nb1[j];
        #pragma unroll
        for (int i = 0; i < 16; ++i) a = fmaf(o[i], nw1[i*16+j], a);
        h[j] = fmaxf(a, 0.f);
    }
    float xn[16];
    #pragma unroll
    for (int j = 0; j < 16; ++j) {
        float a = nb2[j];
        #pragma unroll
        for (int i = 0; i < 16; ++i) a = fmaf(h[i], nw2[i*16+j], a);
        xn[j] = fmaxf(a, 0.f);
    }
    float g[16];
    #pragma unroll
    for (int j = 0; j < 16; ++j) {
        float a = hb1[j];
        #pragma unroll
        for (int i = 0; i < 16; ++i) a = fmaf(xn[i], hw1[i*16+j], a);
        g[j] = fmaxf(a, 0.f);
    }
    #pragma unroll
    for (int k = 0; k < 3; ++k) {
        float a = hb2[k];
        #pragma unroll
        for (int i = 0; i < 16; ++i) a = fmaf(g[i], hw2[i*3+k], a);
        out_n[(size_t)n*3 + k] = a;
    }
}

// ---- fused convs: slot-parallel MLP + block-level SEGMENTED reduction ----

// conv1: MLP from ea; msg3. NE = 12500*256 exactly -> every block full.
__global__ void conv1E(const unsigned long long* __restrict__ srec,
                       const unsigned int* __restrict__ ea_s,
                       const unsigned short* __restrict__ nrec, const unsigned short* __restrict__ Pcb,
                       const float* __restrict__ ew1, const float* __restrict__ eb1,
                       const float* __restrict__ ew2, const float* __restrict__ eb2,
                       unsigned short* __restrict__ ebuf, float* agg) {
    __shared__ float smsg[256 * 5];
    __shared__ int st_[256];
    __shared__ int scn[256];
    __shared__ int segofs[257];
    __shared__ int nsegS;
    int tid = threadIdx.x;
    int j = blockIdx.x * 256 + tid;
    unsigned long long sr = srec[j];
    int s = (int)(sr & 0x1FFFFu);
    int t = (int)((sr >> 17) & 0x1FFFFu);
    float pa[16], xv[16], pc[16];
    ld_nrec16(nrec + (size_t)s*32, pa, xv);
    ldbf16x16(Pcb + (size_t)t*16, pc);
    uint2 eaw = *reinterpret_cast<const uint2*>(&ea_s[(size_t)2*j]);
    float e0 = bf2f(eaw.x & 0xffffu), e1 = bf2f(eaw.x >> 16), e2 = bf2f(eaw.y & 0xffffu);
    float h[16];
    #pragma unroll
    for (int jj = 0; jj < 16; ++jj) {
        float a = pa[jj] + pc[jj] + eb1[jj]
                + e0*ew1[3*16+jj] + e1*ew1[4*16+jj] + e2*ew1[5*16+jj];
        h[jj] = fmaxf(a, 0.f);
    }
    float h2[16];
    #pragma unroll
    for (int jj = 0; jj < 16; ++jj) {
        float a = eb2[jj];
        #pragma unroll
        for (int i = 0; i < 16; ++i) a = fmaf(h[i], ew2[i*16+jj], a);
        h2[jj] = fmaxf(a, 0.f);
    }
    stbf16x16(ebuf + (size_t)j*16, h2);
    st_[tid] = t;
    smsg[tid*5 + 0] = fmaxf(xv[0] + e0, 0.f);
    smsg[tid*5 + 1] = fmaxf(xv[1] + e1, 0.f);
    smsg[tid*5 + 2] = fmaxf(xv[2] + e2, 0.f);
    __syncthreads();
    int flag = (tid == 0 || st_[tid-1] != t) ? 1 : 0;
    scn[tid] = flag; __syncthreads();
    for (int off = 1; off < 256; off <<= 1) {
        int u = (tid >= off) ? scn[tid - off] : 0;
        __syncthreads();
        scn[tid] += u;
        __syncthreads();
    }
    if (flag) segofs[scn[tid] - 1] = tid;
    if (tid == 255) { nsegS = scn[255]; segofs[scn[255]] = 256; }
    __syncthreads();
    int nseg = nsegS;
    for (int p = tid; p < nseg * 4; p += 256) {
        int seg = p >> 2, d = p & 3;
        if (d == 3) continue;
        int k0 = segofs[seg], k1 = segofs[seg + 1];
        float a = 0.f;
        for (int k = k0; k < k1; ++k) a += smsg[k*5 + d];
        int node = st_[k0];
        if (seg == 0 || seg == nseg - 1)
            atomicAdd(&agg[(size_t)node*16 + d], a);
        else
            agg[(size_t)node*16 + d] = a;
    }
}

// conv2/3: MLP from ebuf (in place); msg16.
__global__ void convE(const unsigned long long* __restrict__ srec,
                      unsigned short* ebuf,
                      const unsigned short* __restrict__ nrec, const unsigned short* __restrict__ Pcb,
                      const float* __restrict__ ew1, const float* __restrict__ eb1,
                      const float* __restrict__ ew2, const float* __restrict__ eb2,
                      float* agg) {
    __shared__ float smsg[256 * 17];
    __shared__ int st_[256];
    __shared__ int scn[256];
    __shared__ int segofs[257];
    __shared__ int nsegS;
    int tid = threadIdx.x;
    int j = blockIdx.x * 256 + tid;
    unsigned long long sr = srec[j];
    int s = (int)(sr & 0x1FFFFu);
    int t = (int)((sr >> 17) & 0x1FFFFu);
    float pa[16], xv[16], pc[16], ein[16];
    ld_nrec16(nrec + (size_t)s*32, pa, xv);      // one 64B line: Pa + X
    ldbf16x16(Pcb + (size_t)t*16, pc);           // dst-grouped, cached
    ldbf16x16(ebuf + (size_t)j*16, ein);         // old edge feats (stream)
    float h[16];
    #pragma unroll
    for (int jj = 0; jj < 16; ++jj) h[jj] = pa[jj] + pc[jj] + eb1[jj];
    #pragma unroll
    for (int i = 0; i < 16; ++i) {
        #pragma unroll
        for (int jj = 0; jj < 16; ++jj) h[jj] = fmaf(ein[i], ew1[(16+i)*16+jj], h[jj]);
    }
    #pragma unroll
    for (int jj = 0; jj < 16; ++jj) h[jj] = fmaxf(h[jj], 0.f);
    float h2[16];
    #pragma unroll
    for (int jj = 0; jj < 16; ++jj) {
        float a = eb2[jj];
        #pragma unroll
        for (int i = 0; i < 16; ++i) a = fmaf(h[i], ew2[i*16+jj], a);
        h2[jj] = fmaxf(a, 0.f);
    }
    stbf16x16(ebuf + (size_t)j*16, h2);          // full 32B row, in place
    st_[tid] = t;
    #pragma unroll
    for (int d = 0; d < 16; ++d) smsg[tid*17 + d] = fmaxf(xv[d] + ein[d], 0.f);
    __syncthreads();
    int flag = (tid == 0 || st_[tid-1] != t) ? 1 : 0;
    scn[tid] = flag; __syncthreads();
    for (int off = 1; off < 256; off <<= 1) {
        int u = (tid >= off) ? scn[tid - off] : 0;
        __syncthreads();
        scn[tid] += u;
        __syncthreads();
    }
    if (flag) segofs[scn[tid] - 1] = tid;
    if (tid == 255) { nsegS = scn[255]; segofs[scn[255]] = 256; }
    __syncthreads();
    int nseg = nsegS;
    for (int p = tid; p < nseg * 16; p += 256) {
        int seg = p >> 4, d = p & 15;
        int k0 = segofs[seg], k1 = segofs[seg + 1];
        float a = 0.f;
        for (int k = k0; k < k1; ++k) a += smsg[k*17 + d];
        int node = st_[k0];
        if (seg == 0 || seg == nseg - 1)
            atomicAdd(&agg[(size_t)node*16 + d], a);   // boundary: <=2 segs/block
        else
            agg[(size_t)node*16 + d] = a;              // interior: plain store
    }
}

// conv3 edge head: stream ebuf3 + srec -> out_e scatter (after node_last).
__global__ void khead(const unsigned long long* __restrict__ srec,
                      const unsigned short* __restrict__ ebuf,
                      const float* __restrict__ hw1, const float* __restrict__ hb1,
                      const float* __restrict__ hw2, const float* __restrict__ hb2,
                      float* __restrict__ out_e) {
    int j = blockIdx.x * blockDim.x + threadIdx.x;
    if (j >= NE) return;
    unsigned long long sr = srec[j];
    int e = (int)(sr >> 34);
    float h2[16];
    ldbf16x16(ebuf + (size_t)j*16, h2);
    float g[16];
    #pragma unroll
    for (int jj = 0; jj < 16; ++jj) {
        float a = hb1[jj];
        #pragma unroll
        for (int i = 0; i < 16; ++i) a = fmaf(h2[i], hw1[i*16+jj], a);
        g[jj] = fmaxf(a, 0.f);
    }
    #pragma unroll
    for (int k = 0; k < 3; ++k) {
        float a = hb2[k];
        #pragma unroll
        for (int i = 0; i < 16; ++i) a = fmaf(g[i], hw2[i*3+k], a);
        out_e[(size_t)e*3 + k] = a;
    }
}

extern "C" void kernel_launch(void* const* d_in, const int* in_sizes, int n_in,
                              void* d_out, int out_size, void* d_ws, size_t ws_size,
                              hipStream_t stream) {
    const float* x  = (const float*)d_in[0];
    const float* ea = (const float*)d_in[1];
    const int*   ei = (const int*)d_in[2];
    const float *c1_ew1 = (const float*)d_in[3],  *c1_eb1 = (const float*)d_in[4];
    const float *c1_ew2 = (const float*)d_in[5],  *c1_eb2 = (const float*)d_in[6];
    const float *c1_nw1 = (const float*)d_in[7],  *c1_nb1 = (const float*)d_in[8];
    const float *c1_nw2 = (const float*)d_in[9],  *c1_nb2 = (const float*)d_in[10];
    const float *c2_ew1 = (const float*)d_in[11], *c2_eb1 = (const float*)d_in[12];
    const float *c2_ew2 = (const float*)d_in[13], *c2_eb2 = (const float*)d_in[14];
    const float *c2_nw1 = (const float*)d_in[15], *c2_nb1 = (const float*)d_in[16];
    const float *c2_nw2 = (const float*)d_in[17], *c2_nb2 = (const float*)d_in[18];
    const float *c3_ew1 = (const float*)d_in[19], *c3_eb1 = (const float*)d_in[20];
    const float *c3_ew2 = (const float*)d_in[21], *c3_eb2 = (const float*)d_in[22];
    const float *c3_nw1 = (const float*)d_in[23], *c3_nb1 = (const float*)d_in[24];
    const float *c3_nw2 = (const float*)d_in[25], *c3_nb2 = (const float*)d_in[26];
    const float *node_w1 = (const float*)d_in[27], *node_b1 = (const float*)d_in[28];
    const float *node_w2 = (const float*)d_in[29], *node_b2 = (const float*)d_in[30];
    const float *edge_w1 = (const float*)d_in[31], *edge_b1 = (const float*)d_in[32];
    const float *edge_w2 = (const float*)d_in[33], *edge_b2 = (const float*)d_in[34];

    // ---- ws carve-up (137.6 MB) ----
    char* w = (char*)d_ws;
    unsigned short* ebuf = (unsigned short*)w;               // NE*32; build scratch aliases inside:
    uint4* brec16 = (uint4*)w;                               //   NE*16 = 51.2 MB
    int* hist   = (int*)(w + (size_t)NE*16);                 //   NBKT*NBLK1*4 = 3.2 MB
    int* binsum = hist + NBKT * NBLK1;
    int* binbase = binsum + NBKT;
    w += (size_t)NE * 32;
    unsigned long long* srec = (unsigned long long*)w;  w += (size_t)NE * 8;   // 25.6 MB
    unsigned short* nrec = (unsigned short*)w;          w += (size_t)NN * 64;  // 6.4 MB
    unsigned short* Pc   = (unsigned short*)w;          w += (size_t)NN * 32;  // 3.2 MB

    // ---- d_out overlays ----
    float* out_n = (float*)d_out;                      // N*3 floats
    float* out_e = out_n + (size_t)NN * 3;             // E*3 floats
    int* start = (int*)out_n;                          // build scratch, dead before node_last
    unsigned int* ea_s = (unsigned int*)out_e;                 // NE*8 = 25.6 MB
    float* agg = (float*)((char*)out_e + (size_t)NE * 8);      // N*16 f32 = 6.4 MB

    const int B = 256;
    const int gn = (NN + B - 1) / B;                 // 391
    const int ge = NE / B;                           // 12500 exact
    const int gz = (NN * 16 / 4 + B - 1) / B;        // 1563

    // ---- build (no global atomics) ----
    khist1<<<NBLK1, B, 0, stream>>>(ei, hist);
    kscan_a<<<NBKT, NBLK1, 0, stream>>>(hist, binsum);
    kscan_b<<<1, 1024, 0, stream>>>(binsum, binbase, start);
    kscatter1<<<NBLK1, B, 0, stream>>>(ei, ea, hist, binbase, brec16);
    kbucket<<<NBKT, B, 0, stream>>>(brec16, binbase, srec, ea_s, start);

    // ---- conv1 (conv1E clobbers brec16/hist/binbase region via ebuf — all dead) ----
    prep1<<<gn, B, 0, stream>>>(x, c1_ew1, nrec, Pc);
    kzero<<<gz, B, 0, stream>>>((float4*)agg, NN * 16 / 4);
    conv1E<<<ge, B, 0, stream>>>(srec, ea_s, nrec, Pc,
                                 c1_ew1, c1_eb1, c1_ew2, c1_eb2, ebuf, agg);
    conv1_node<<<gn, B, 0, stream>>>(agg, x, c1_nw1, c1_nb1, c1_nw2, c1_nb2,
                                     c2_ew1, nrec, Pc);
    // ---- conv2 ----
    kzero<<<gz, B, 0, stream>>>((float4*)agg, NN * 16 / 4);
    convE<<<ge, B, 0, stream>>>(srec, ebuf, nrec, Pc,
                                c2_ew1, c2_eb1, c2_ew2, c2_eb2, agg);
    node_mid<<<gn, B, 0, stream>>>(agg, c2_nw1, c2_nb1, c2_nw2, c2_nb2,
                                   c3_ew1, nrec, Pc);
    // ---- conv3 (convE writes agg; node_last consumes agg + writes out_n;
    //      khead finally overwrites ea_s/agg region with real out_e) ----
    kzero<<<gz, B, 0, stream>>>((float4*)agg, NN * 16 / 4);
    convE<<<ge, B, 0, stream>>>(srec, ebuf, nrec, Pc,
                                c3_ew1, c3_eb1, c3_ew2, c3_eb2, agg);
    node_last<<<gn, B, 0, stream>>>(agg, nrec, c3_nw1, c3_nb1, c3_nw2, c3_nb2,
                                    node_w1, node_b1, node_w2, node_b2, out_n);
    khead<<<ge, B, 0, stream>>>(srec, ebuf, edge_w1, edge_b1, edge_w2, edge_b2, out_e);
}